// Round 7
// baseline (616.583 us; speedup 1.0000x reference)
//
#include <hip/hip_runtime.h>
#include <math.h>

#define NQ    12
#define DIM   4096        // 2^NQ
#define K_EXT 8192        // [hi | lo] extended row
#define NSAMP 2048
#define NLAY  3
#define NT    32          // 2048/64 tiles per dimension
#define NTRI  528         // NT*(NT+1)/2 triangular blocks
#define BKG   128         // k per staged tile
#define LDKG  136         // LDS row stride in ushort (272 B, 16B-aligned; 17 odd -> 2-way read phases)

typedef __attribute__((ext_vector_type(8))) short bf16x8;   // 8 bf16 = 4 VGPRs
typedef __attribute__((ext_vector_type(4))) float floatx4;  // MFMA 16x16 acc

__device__ __forceinline__ unsigned short f32_to_bf16(float x) {
    unsigned u = __builtin_bit_cast(unsigned, x);
    u += 0x7FFFu + ((u >> 16) & 1u);            // round-to-nearest-even
    return (unsigned short)(u >> 16);
}
__device__ __forceinline__ float bf16_to_f32(unsigned short h) {
    unsigned u = (unsigned)h << 16;
    return __builtin_bit_cast(float, u);
}

// ---------------------------------------------------------------------------
// Kernel 1: one SAMPLE PER WAVE, state in registers (64 amps/lane).
// Amp index i = reg*64 + lane: bits 0-5 = lane (shfl gates), bits 6-11 = reg
// (in-register butterflies).  Zero barriers in the gate loop.
// CZ parity: popc(i & ror1(i)) = P_lane(lane) ^ P_reg(r) ^ (l5&r0) ^ (l0&r5),
// with P_reg/r0/r5 compile-time per unrolled r.
// Emits psi = hi + lo as one extended bf16 row [hi(4096) | lo(4096)].
// ---------------------------------------------------------------------------
__global__ __launch_bounds__(256) void sim_kernel(const float* __restrict__ data,
                                                  const float* __restrict__ params,
                                                  unsigned short* __restrict__ pe)
{
    __shared__ float CS[4*36], SN[4*36];
    const int tid  = threadIdx.x;
    const int wave = tid >> 6, lane = tid & 63;
    const int smp  = blockIdx.x * 4 + wave;

    if (lane < NLAY*NQ) {
        const int q = lane % NQ;
        const float th = 0.5f * (params[lane] + data[smp*NQ + q]);
        CS[wave*36 + lane] = cosf(th);
        SN[wave*36 + lane] = sinf(th);
    }
    __syncthreads();

    float v[64];
    #pragma unroll
    for (int r = 0; r < 64; ++r) v[r] = 0.f;
    if (lane == 0) v[0] = 1.f;

    // CZ lane-side sign bases (see header comment)
    const int pl = __popc(lane & (lane >> 1) & 0x1F) & 1;
    const int l0 = lane & 1, l5 = (lane >> 5) & 1;
    const float f00 = pl ? -1.f : 1.f;
    const float f10 = (pl ^ l5) ? -1.f : 1.f;
    const float f01 = (pl ^ l0) ? -1.f : 1.f;
    const float f11 = (pl ^ l5 ^ l0) ? -1.f : 1.f;

    for (int l = 0; l < NLAY; ++l) {
        const float* cs = &CS[wave*36 + l*NQ];
        const float* sn = &SN[wave*36 + l*NQ];
        // qubits 0-5 (lane bits): v' = c*v + t*partner, t = (bit? +s : -s)
        #pragma unroll
        for (int q = 0; q < 6; ++q) {
            const float c = cs[q], s = sn[q];
            const float t = ((lane >> q) & 1) ? s : -s;
            #pragma unroll
            for (int r = 0; r < 64; ++r) {
                const float p = __shfl_xor(v[r], 1 << q, 64);
                v[r] = c * v[r] + t * p;
            }
        }
        // qubits 6-11 (register bits): standard butterfly
        #pragma unroll
        for (int b = 0; b < 6; ++b) {
            const float c = cs[6 + b], s = sn[6 + b];
            const int M = 1 << b;
            #pragma unroll
            for (int r = 0; r < 64; ++r) {
                if (!(r & M)) {
                    const float a0 = v[r], a1 = v[r | M];
                    v[r]     = c * a0 - s * a1;
                    v[r | M] = s * a0 + c * a1;
                }
            }
        }
        // CZ ring sign
        #pragma unroll
        for (int r = 0; r < 64; ++r) {
            const int pr = __popc(r & (r >> 1) & 0x1F) & 1;
            const int r0 = r & 1, r5 = (r >> 5) & 1;
            float f = r0 ? (r5 ? f11 : f10) : (r5 ? f01 : f00);
            if (pr) f = -f;
            v[r] *= f;
        }
    }

    unsigned short* outh = pe + (size_t)smp * K_EXT;
    unsigned short* outl = outh + DIM;
    #pragma unroll
    for (int r = 0; r < 64; ++r) {
        const float x = v[r];
        const unsigned short hb = f32_to_bf16(x);
        outh[r*64 + lane] = hb;
        outl[r*64 + lane] = f32_to_bf16(x - bf16_to_f32(hb));
    }
}

// ---------------------------------------------------------------------------
// Kernel 2: bf16 Gram over K_EXT=8192 + fused reduction, triangular grid.
// 64x64 tile/block; BK=128 stage; 4 waves K-split (32-k slices); each wave
// computes the FULL 64x64 tile as 4x4 frags of mfma_f32_16x16x32_bf16
// (16 MFMA : 8 ds_read_b128 = 32 FLOP/LDS-byte).  2-deep register prefetch.
// Wave K-partials summed in LDS (aliased over staging) before squaring.
// ---------------------------------------------------------------------------
__global__ __launch_bounds__(256, 2) void gram_kernel(const unsigned short* __restrict__ pe,
                                                      const int* __restrict__ labels,
                                                      double* __restrict__ part1,
                                                      double* __restrict__ part2)
{
    __shared__ __align__(16) unsigned short stage[2*64*LDKG];   // A | B, 34.8 KiB
    __shared__ float la[64], lb[64];

    unsigned short* As = stage;
    unsigned short* Bs = stage + 64*LDKG;
    float*  Gt  = (float*)stage;       // alias: live after main loop (64 x 66)
    double* red = (double*)stage;      // alias: live after Gt reads complete

    const int tid = threadIdx.x;
    const int bid = blockIdx.x;

    // triangular index -> (bi,bj), bj >= bi
    int bi = (int)((65.0 - sqrt(65.0*65.0 - 8.0*(double)bid)) * 0.5);
    int start = bi*(65-bi)/2;
    while (bid < start)              { --bi; start = bi*(65-bi)/2; }
    while (bid >= start + (NT - bi)) { start += NT - bi; ++bi; }
    const int bj = bi + (bid - start);

    if (tid < 64)       la[tid]      = 2.0f*(float)labels[bi*64 + tid]      - 1.0f;
    else if (tid < 128) lb[tid - 64] = 2.0f*(float)labels[bj*64 + tid - 64] - 1.0f;

    const int wave = tid >> 6, lane = tid & 63;
    const int m  = lane & 15;          // A/B layout: lane holds M[lane&15][(lane>>4)*8+j]
    const int g  = lane >> 4;
    const int ks = wave * 32;          // this wave's k-slice within the stage

    floatx4 acc[4][4];
    #pragma unroll
    for (int fi = 0; fi < 4; ++fi)
        #pragma unroll
        for (int fj = 0; fj < 4; ++fj) acc[fi][fj] = (floatx4){0.f,0.f,0.f,0.f};

    // staging map: threads 0-127 stage A, 128-255 stage B; (row, half-row)
    const int sbuf  = tid >> 7;
    const int srow  = (tid >> 1) & 63;
    const int shalf = tid & 1;
    const unsigned short* gptr = pe + ((size_t)((sbuf ? bj : bi)*64 + srow)) * K_EXT + shalf*64;
    unsigned short* sptr = (sbuf ? Bs : As) + srow*LDKG + shalf*64;

    // prologue: stage 0 -> P, stage 1 -> Q
    uint4 P[8], Q[8];
    #pragma unroll
    for (int j = 0; j < 8; ++j) P[j] = *(const uint4*)(gptr + j*8);
    #pragma unroll
    for (int j = 0; j < 8; ++j) Q[j] = *(const uint4*)(gptr + BKG + j*8);

    for (int kk = 0; kk < K_EXT; kk += 2*BKG) {
        // ---- stage kk ----
        __syncthreads();                       // prev readers done
        #pragma unroll
        for (int j = 0; j < 8; ++j) *(uint4*)(sptr + j*8) = P[j];
        __syncthreads();
        if (kk + 2*BKG < K_EXT) {
            #pragma unroll
            for (int j = 0; j < 8; ++j) P[j] = *(const uint4*)(gptr + kk + 2*BKG + j*8);
        }
        {
            bf16x8 a[4], b[4];
            #pragma unroll
            for (int fi = 0; fi < 4; ++fi) a[fi] = *(const bf16x8*)&As[(fi*16 + m)*LDKG + ks + g*8];
            #pragma unroll
            for (int fj = 0; fj < 4; ++fj) b[fj] = *(const bf16x8*)&Bs[(fj*16 + m)*LDKG + ks + g*8];
            #pragma unroll
            for (int fi = 0; fi < 4; ++fi)
                #pragma unroll
                for (int fj = 0; fj < 4; ++fj)
                    acc[fi][fj] = __builtin_amdgcn_mfma_f32_16x16x32_bf16(a[fi], b[fj], acc[fi][fj], 0, 0, 0);
        }
        // ---- stage kk+BKG ----
        __syncthreads();
        #pragma unroll
        for (int j = 0; j < 8; ++j) *(uint4*)(sptr + j*8) = Q[j];
        __syncthreads();
        if (kk + 3*BKG < K_EXT) {
            #pragma unroll
            for (int j = 0; j < 8; ++j) Q[j] = *(const uint4*)(gptr + kk + 3*BKG + j*8);
        }
        {
            bf16x8 a[4], b[4];
            #pragma unroll
            for (int fi = 0; fi < 4; ++fi) a[fi] = *(const bf16x8*)&As[(fi*16 + m)*LDKG + ks + g*8];
            #pragma unroll
            for (int fj = 0; fj < 4; ++fj) b[fj] = *(const bf16x8*)&Bs[(fj*16 + m)*LDKG + ks + g*8];
            #pragma unroll
            for (int fi = 0; fi < 4; ++fi)
                #pragma unroll
                for (int fj = 0; fj < 4; ++fj)
                    acc[fi][fj] = __builtin_amdgcn_mfma_f32_16x16x32_bf16(a[fi], b[fj], acc[fi][fj], 0, 0, 0);
        }
    }

    __syncthreads();   // all staging reads done; stage memory reusable as Gt

    // Sum the 4 wave K-partials into Gt.  C/D layout (m89):
    // row = (lane>>4)*4 + reg, col = lane&15 (per 16x16 frag).
    const int crow = g * 4;
    for (int w = 0; w < 4; ++w) {
        if (wave == w) {
            #pragma unroll
            for (int fi = 0; fi < 4; ++fi)
                #pragma unroll
                for (int fj = 0; fj < 4; ++fj)
                    #pragma unroll
                    for (int r = 0; r < 4; ++r) {
                        const int row = fi*16 + crow + r;
                        const int col = fj*16 + m;
                        if (w == 0) Gt[row*66 + col]  = acc[fi][fj][r];
                        else        Gt[row*66 + col] += acc[fi][fj][r];
                    }
        }
        __syncthreads();
    }

    // Reduce: s1 += w*l_i*l_j*G^2, s2 += w*G^4 (w = 2 above diag, 1 on, 0 below)
    double s1 = 0.0, s2 = 0.0;
    #pragma unroll
    for (int u = 0; u < 16; ++u) {
        const int e   = u*256 + tid;
        const int row = e >> 6, col = e & 63;
        const float gv = Gt[row*66 + col];
        const float w  = (bi < bj) ? 2.0f : ((row < col) ? 2.0f : ((row == col) ? 1.0f : 0.0f));
        const float g2 = gv * gv;
        s1 += (double)(w * la[row] * lb[col] * g2);
        const double d = (double)g2;
        s2 += (double)w * d * d;
    }
    __syncthreads();   // Gt reads done before red alias is written

    red[tid] = s1; __syncthreads();
    for (int off = 128; off; off >>= 1) { if (tid < off) red[tid] += red[tid+off]; __syncthreads(); }
    if (tid == 0) part1[bid] = red[0];
    __syncthreads();
    red[tid] = s2; __syncthreads();
    for (int off = 128; off; off >>= 1) { if (tid < off) red[tid] += red[tid+off]; __syncthreads(); }
    if (tid == 0) part2[bid] = red[0];
}

// ---------------------------------------------------------------------------
// Kernel 3: reduce 528 partial slots -> scalar f32.
// square_sum_l = N^2 exactly, so out = s1 / (N * sqrt(s2)).
// ---------------------------------------------------------------------------
__global__ __launch_bounds__(256) void finalize_kernel(const double* __restrict__ part1,
                                                       const double* __restrict__ part2,
                                                       float* __restrict__ out)
{
    __shared__ double r1[256], r2[256];
    const int tid = threadIdx.x;
    double a = 0.0, b = 0.0;
    #pragma unroll
    for (int u = 0; u < 3; ++u) {
        const int s = tid + u*256;
        if (s < NTRI) { a += part1[s]; b += part2[s]; }
    }
    r1[tid] = a; r2[tid] = b; __syncthreads();
    for (int off = 128; off; off >>= 1) {
        if (tid < off) { r1[tid] += r1[tid+off]; r2[tid] += r2[tid+off]; }
        __syncthreads();
    }
    if (tid == 0) out[0] = (float)(r1[0] / (sqrt(r2[0]) * (double)NSAMP));
}

// ---------------------------------------------------------------------------
extern "C" void kernel_launch(void* const* d_in, const int* in_sizes, int n_in,
                              void* d_out, int out_size, void* d_ws, size_t ws_size,
                              hipStream_t stream)
{
    const float* data   = (const float*)d_in[0]; // (2048,12) f32
    const int*   labels = (const int*)d_in[1];   // (2048,)   i32
    const float* params = (const float*)d_in[2]; // (3,12)    f32

    double* part1 = (double*)d_ws;                                    // 528 doubles
    double* part2 = part1 + NTRI;                                     // 528 doubles
    unsigned short* psi_ext = (unsigned short*)((char*)d_ws + 16384); // 2048x8192 bf16 = 32 MiB

    sim_kernel<<<NSAMP/4, 256, 0, stream>>>(data, params, psi_ext);
    gram_kernel<<<NTRI, 256, 0, stream>>>(psi_ext, labels, part1, part2);
    finalize_kernel<<<1, 256, 0, stream>>>(part1, part2, (float*)d_out);
}

// Round 8
// 608.122 us; speedup vs baseline: 1.0139x; 1.0139x over previous
//
#include <hip/hip_runtime.h>
#include <math.h>

#define NQ    12
#define DIM   4096        // 2^NQ
#define K_EXT 8192        // [hi | lo] extended row
#define NSAMP 2048
#define NLAY  3
#define NT    32          // 2048/64 tiles per dimension
#define NTRI  528         // NT*(NT+1)/2 triangular blocks
#define BKG   128         // k per staged tile
#define LDKG  136         // LDS row stride in ushort (272 B; granule stride 17 -> 2-way b128 phases, free)

typedef __attribute__((ext_vector_type(8))) short bf16x8;   // 8 bf16 = 4 VGPRs
typedef __attribute__((ext_vector_type(4))) float floatx4;  // MFMA 16x16 acc

__device__ __forceinline__ unsigned short f32_to_bf16(float x) {
    unsigned u = __builtin_bit_cast(unsigned, x);
    u += 0x7FFFu + ((u >> 16) & 1u);            // round-to-nearest-even
    return (unsigned short)(u >> 16);
}
__device__ __forceinline__ float bf16_to_f32(unsigned short h) {
    unsigned u = (unsigned)h << 16;
    return __builtin_bit_cast(float, u);
}

// ---------------------------------------------------------------------------
// Kernel 1: one SAMPLE PER WAVE, state in registers (64 amps/lane).
// Amp index i = reg*64 + lane: bits 0-5 = lane (shfl gates), bits 6-11 = reg
// (in-register butterflies).  Zero barriers in the gate loop.
// CZ parity: popc(i & ror1(i)) = P_lane(lane) ^ P_reg(r) ^ (l5&r0) ^ (l0&r5).
// Emits psi = hi + lo as one extended bf16 row [hi(4096) | lo(4096)].
// ---------------------------------------------------------------------------
__global__ __launch_bounds__(256) void sim_kernel(const float* __restrict__ data,
                                                  const float* __restrict__ params,
                                                  unsigned short* __restrict__ pe)
{
    __shared__ float CS[4*36], SN[4*36];
    const int tid  = threadIdx.x;
    const int wave = tid >> 6, lane = tid & 63;
    const int smp  = blockIdx.x * 4 + wave;

    if (lane < NLAY*NQ) {
        const int q = lane % NQ;
        const float th = 0.5f * (params[lane] + data[smp*NQ + q]);
        CS[wave*36 + lane] = cosf(th);
        SN[wave*36 + lane] = sinf(th);
    }
    __syncthreads();

    float v[64];
    #pragma unroll
    for (int r = 0; r < 64; ++r) v[r] = 0.f;
    if (lane == 0) v[0] = 1.f;

    const int pl = __popc(lane & (lane >> 1) & 0x1F) & 1;
    const int l0 = lane & 1, l5 = (lane >> 5) & 1;
    const float f00 = pl ? -1.f : 1.f;
    const float f10 = (pl ^ l5) ? -1.f : 1.f;
    const float f01 = (pl ^ l0) ? -1.f : 1.f;
    const float f11 = (pl ^ l5 ^ l0) ? -1.f : 1.f;

    for (int l = 0; l < NLAY; ++l) {
        const float* cs = &CS[wave*36 + l*NQ];
        const float* sn = &SN[wave*36 + l*NQ];
        #pragma unroll
        for (int q = 0; q < 6; ++q) {
            const float c = cs[q], s = sn[q];
            const float t = ((lane >> q) & 1) ? s : -s;
            #pragma unroll
            for (int r = 0; r < 64; ++r) {
                const float p = __shfl_xor(v[r], 1 << q, 64);
                v[r] = c * v[r] + t * p;
            }
        }
        #pragma unroll
        for (int b = 0; b < 6; ++b) {
            const float c = cs[6 + b], s = sn[6 + b];
            const int M = 1 << b;
            #pragma unroll
            for (int r = 0; r < 64; ++r) {
                if (!(r & M)) {
                    const float a0 = v[r], a1 = v[r | M];
                    v[r]     = c * a0 - s * a1;
                    v[r | M] = s * a0 + c * a1;
                }
            }
        }
        #pragma unroll
        for (int r = 0; r < 64; ++r) {
            const int pr = __popc(r & (r >> 1) & 0x1F) & 1;
            const int r0 = r & 1, r5 = (r >> 5) & 1;
            float f = r0 ? (r5 ? f11 : f10) : (r5 ? f01 : f00);
            if (pr) f = -f;
            v[r] *= f;
        }
    }

    unsigned short* outh = pe + (size_t)smp * K_EXT;
    unsigned short* outl = outh + DIM;
    #pragma unroll
    for (int r = 0; r < 64; ++r) {
        const float x = v[r];
        const unsigned short hb = f32_to_bf16(x);
        outh[r*64 + lane] = hb;
        outl[r*64 + lane] = f32_to_bf16(x - bf16_to_f32(hb));
    }
}

// ---------------------------------------------------------------------------
// Kernel 2: bf16 Gram over K_EXT=8192 + fused reduction, triangular grid.
// 64x64 tile/block; BK=128 stage; 4 waves K-split (32-k slices); each wave
// computes the FULL 64x64 tile as 4x4 frags of mfma_f32_16x16x32_bf16
// (16 MFMA : 8 ds_read_b128 = 32 FLOP/LDS-byte).
// ONE-deep register prefetch (P[8] = 32 VGPRs) — R7's two-deep variant
// spilled to scratch (1 GB HBM writes) under __launch_bounds__(256,2).
// Plain launch bounds: ~100 VGPR + 64 AGPR unified, no spill.
// ---------------------------------------------------------------------------
__global__ __launch_bounds__(256) void gram_kernel(const unsigned short* __restrict__ pe,
                                                   const int* __restrict__ labels,
                                                   double* __restrict__ part1,
                                                   double* __restrict__ part2)
{
    __shared__ __align__(16) unsigned short stage[2*64*LDKG];   // A | B, 34.8 KiB
    __shared__ float la[64], lb[64];

    unsigned short* As = stage;
    unsigned short* Bs = stage + 64*LDKG;
    float*  Gt  = (float*)stage;       // alias: live after main loop (64 x 66)
    double* red = (double*)stage;      // alias: live after Gt reads complete

    const int tid = threadIdx.x;
    const int bid = blockIdx.x;

    // triangular index -> (bi,bj), bj >= bi
    int bi = (int)((65.0 - sqrt(65.0*65.0 - 8.0*(double)bid)) * 0.5);
    int start = bi*(65-bi)/2;
    while (bid < start)              { --bi; start = bi*(65-bi)/2; }
    while (bid >= start + (NT - bi)) { start += NT - bi; ++bi; }
    const int bj = bi + (bid - start);

    if (tid < 64)       la[tid]      = 2.0f*(float)labels[bi*64 + tid]      - 1.0f;
    else if (tid < 128) lb[tid - 64] = 2.0f*(float)labels[bj*64 + tid - 64] - 1.0f;

    const int wave = tid >> 6, lane = tid & 63;
    const int m  = lane & 15;          // A/B layout: lane holds M[lane&15][(lane>>4)*8+j]
    const int g  = lane >> 4;
    const int ks = wave * 32;          // this wave's k-slice within the stage

    floatx4 acc[4][4];
    #pragma unroll
    for (int fi = 0; fi < 4; ++fi)
        #pragma unroll
        for (int fj = 0; fj < 4; ++fj) acc[fi][fj] = (floatx4){0.f,0.f,0.f,0.f};

    // staging map: threads 0-127 stage A, 128-255 stage B; (row, half-row)
    const int sbuf  = tid >> 7;
    const int srow  = (tid >> 1) & 63;
    const int shalf = tid & 1;
    const unsigned short* gptr = pe + ((size_t)((sbuf ? bj : bi)*64 + srow)) * K_EXT + shalf*64;
    unsigned short* sptr = (sbuf ? Bs : As) + srow*LDKG + shalf*64;

    // prologue: stage 0 -> P
    uint4 P[8];
    #pragma unroll
    for (int j = 0; j < 8; ++j) P[j] = *(const uint4*)(gptr + j*8);

    for (int kk = 0; kk < K_EXT; kk += BKG) {
        __syncthreads();                       // prev readers done
        #pragma unroll
        for (int j = 0; j < 8; ++j) *(uint4*)(sptr + j*8) = P[j];
        __syncthreads();
        if (kk + BKG < K_EXT) {                // prefetch next stage during compute
            #pragma unroll
            for (int j = 0; j < 8; ++j) P[j] = *(const uint4*)(gptr + kk + BKG + j*8);
        }
        bf16x8 a[4], b[4];
        #pragma unroll
        for (int fi = 0; fi < 4; ++fi) a[fi] = *(const bf16x8*)&As[(fi*16 + m)*LDKG + ks + g*8];
        #pragma unroll
        for (int fj = 0; fj < 4; ++fj) b[fj] = *(const bf16x8*)&Bs[(fj*16 + m)*LDKG + ks + g*8];
        #pragma unroll
        for (int fi = 0; fi < 4; ++fi)
            #pragma unroll
            for (int fj = 0; fj < 4; ++fj)
                acc[fi][fj] = __builtin_amdgcn_mfma_f32_16x16x32_bf16(a[fi], b[fj], acc[fi][fj], 0, 0, 0);
    }

    __syncthreads();   // all staging reads done; stage memory reusable as Gt

    // Sum the 4 wave K-partials into Gt.  C/D layout (m89):
    // row = (lane>>4)*4 + reg, col = lane&15 (per 16x16 frag).
    const int crow = g * 4;
    for (int w = 0; w < 4; ++w) {
        if (wave == w) {
            #pragma unroll
            for (int fi = 0; fi < 4; ++fi)
                #pragma unroll
                for (int fj = 0; fj < 4; ++fj)
                    #pragma unroll
                    for (int r = 0; r < 4; ++r) {
                        const int row = fi*16 + crow + r;
                        const int col = fj*16 + m;
                        if (w == 0) Gt[row*66 + col]  = acc[fi][fj][r];
                        else        Gt[row*66 + col] += acc[fi][fj][r];
                    }
        }
        __syncthreads();
    }

    // Reduce: s1 += w*l_i*l_j*G^2, s2 += w*G^4 (w = 2 above diag, 1 on, 0 below)
    double s1 = 0.0, s2 = 0.0;
    #pragma unroll
    for (int u = 0; u < 16; ++u) {
        const int e   = u*256 + tid;
        const int row = e >> 6, col = e & 63;
        const float gv = Gt[row*66 + col];
        const float w  = (bi < bj) ? 2.0f : ((row < col) ? 2.0f : ((row == col) ? 1.0f : 0.0f));
        const float g2 = gv * gv;
        s1 += (double)(w * la[row] * lb[col] * g2);
        const double d = (double)g2;
        s2 += (double)w * d * d;
    }
    __syncthreads();   // Gt reads done before red alias is written

    red[tid] = s1; __syncthreads();
    for (int off = 128; off; off >>= 1) { if (tid < off) red[tid] += red[tid+off]; __syncthreads(); }
    if (tid == 0) part1[bid] = red[0];
    __syncthreads();
    red[tid] = s2; __syncthreads();
    for (int off = 128; off; off >>= 1) { if (tid < off) red[tid] += red[tid+off]; __syncthreads(); }
    if (tid == 0) part2[bid] = red[0];
}

// ---------------------------------------------------------------------------
// Kernel 3: reduce 528 partial slots -> scalar f32.
// square_sum_l = N^2 exactly, so out = s1 / (N * sqrt(s2)).
// ---------------------------------------------------------------------------
__global__ __launch_bounds__(256) void finalize_kernel(const double* __restrict__ part1,
                                                       const double* __restrict__ part2,
                                                       float* __restrict__ out)
{
    __shared__ double r1[256], r2[256];
    const int tid = threadIdx.x;
    double a = 0.0, b = 0.0;
    #pragma unroll
    for (int u = 0; u < 3; ++u) {
        const int s = tid + u*256;
        if (s < NTRI) { a += part1[s]; b += part2[s]; }
    }
    r1[tid] = a; r2[tid] = b; __syncthreads();
    for (int off = 128; off; off >>= 1) {
        if (tid < off) { r1[tid] += r1[tid+off]; r2[tid] += r2[tid+off]; }
        __syncthreads();
    }
    if (tid == 0) out[0] = (float)(r1[0] / (sqrt(r2[0]) * (double)NSAMP));
}

// ---------------------------------------------------------------------------
extern "C" void kernel_launch(void* const* d_in, const int* in_sizes, int n_in,
                              void* d_out, int out_size, void* d_ws, size_t ws_size,
                              hipStream_t stream)
{
    const float* data   = (const float*)d_in[0]; // (2048,12) f32
    const int*   labels = (const int*)d_in[1];   // (2048,)   i32
    const float* params = (const float*)d_in[2]; // (3,12)    f32

    double* part1 = (double*)d_ws;                                    // 528 doubles
    double* part2 = part1 + NTRI;                                     // 528 doubles
    unsigned short* psi_ext = (unsigned short*)((char*)d_ws + 16384); // 2048x8192 bf16 = 32 MiB

    sim_kernel<<<NSAMP/4, 256, 0, stream>>>(data, params, psi_ext);
    gram_kernel<<<NTRI, 256, 0, stream>>>(psi_ext, labels, part1, part2);
    finalize_kernel<<<1, 256, 0, stream>>>(part1, part2, (float*)d_out);
}

// Round 9
// 201.896 us; speedup vs baseline: 3.0540x; 3.0121x over previous
//
#include <hip/hip_runtime.h>
#include <math.h>

#define NQ    12
#define DIM   4096        // 2^NQ
#define K_EXT 8192        // [hi | lo] extended row
#define NSAMP 2048
#define NLAY  3
#define NT    32          // 2048/64 tiles per dimension
#define NTRI  528         // NT*(NT+1)/2 triangular blocks
#define BK    64
#define LDK   72          // LDS row stride (ushort); 144 B, 16B-aligned rows

typedef __attribute__((ext_vector_type(8)))  short bf16x8;   // 8 bf16 = 4 VGPRs
typedef __attribute__((ext_vector_type(16))) float floatx16; // MFMA 32x32 acc

__device__ __forceinline__ unsigned short f32_to_bf16(float x) {
    unsigned u = __builtin_bit_cast(unsigned, x);
    u += 0x7FFFu + ((u >> 16) & 1u);            // round-to-nearest-even
    return (unsigned short)(u >> 16);
}
__device__ __forceinline__ float bf16_to_f32(unsigned short h) {
    unsigned u = (unsigned)h << 16;
    return __builtin_bit_cast(float, u);
}

// ---------------------------------------------------------------------------
// Kernel 1: one SAMPLE PER WAVE, state in registers (64 amps/lane).
// Amp index i = reg*64 + lane: bits 0-5 = lane (shfl gates), bits 6-11 = reg
// (in-register butterflies).  Zero barriers in the gate loop.
// CZ parity: popc(i & ror1(i)) = P_lane(lane) ^ P_reg(r) ^ (l5&r0) ^ (l0&r5).
// Emits psi = hi + lo as one extended bf16 row [hi(4096) | lo(4096)].
// ---------------------------------------------------------------------------
__global__ __launch_bounds__(256) void sim_kernel(const float* __restrict__ data,
                                                  const float* __restrict__ params,
                                                  unsigned short* __restrict__ pe)
{
    __shared__ float CS[4*36], SN[4*36];
    const int tid  = threadIdx.x;
    const int wave = tid >> 6, lane = tid & 63;
    const int smp  = blockIdx.x * 4 + wave;

    if (lane < NLAY*NQ) {
        const int q = lane % NQ;
        const float th = 0.5f * (params[lane] + data[smp*NQ + q]);
        CS[wave*36 + lane] = cosf(th);
        SN[wave*36 + lane] = sinf(th);
    }
    __syncthreads();

    float v[64];
    #pragma unroll
    for (int r = 0; r < 64; ++r) v[r] = 0.f;
    if (lane == 0) v[0] = 1.f;

    const int pl = __popc(lane & (lane >> 1) & 0x1F) & 1;
    const int l0 = lane & 1, l5 = (lane >> 5) & 1;
    const float f00 = pl ? -1.f : 1.f;
    const float f10 = (pl ^ l5) ? -1.f : 1.f;
    const float f01 = (pl ^ l0) ? -1.f : 1.f;
    const float f11 = (pl ^ l5 ^ l0) ? -1.f : 1.f;

    for (int l = 0; l < NLAY; ++l) {
        const float* cs = &CS[wave*36 + l*NQ];
        const float* sn = &SN[wave*36 + l*NQ];
        #pragma unroll
        for (int q = 0; q < 6; ++q) {
            const float c = cs[q], s = sn[q];
            const float t = ((lane >> q) & 1) ? s : -s;
            #pragma unroll
            for (int r = 0; r < 64; ++r) {
                const float p = __shfl_xor(v[r], 1 << q, 64);
                v[r] = c * v[r] + t * p;
            }
        }
        #pragma unroll
        for (int b = 0; b < 6; ++b) {
            const float c = cs[6 + b], s = sn[6 + b];
            const int M = 1 << b;
            #pragma unroll
            for (int r = 0; r < 64; ++r) {
                if (!(r & M)) {
                    const float a0 = v[r], a1 = v[r | M];
                    v[r]     = c * a0 - s * a1;
                    v[r | M] = s * a0 + c * a1;
                }
            }
        }
        #pragma unroll
        for (int r = 0; r < 64; ++r) {
            const int pr = __popc(r & (r >> 1) & 0x1F) & 1;
            const int r0 = r & 1, r5 = (r >> 5) & 1;
            float f = r0 ? (r5 ? f11 : f10) : (r5 ? f01 : f00);
            if (pr) f = -f;
            v[r] *= f;
        }
    }

    unsigned short* outh = pe + (size_t)smp * K_EXT;
    unsigned short* outl = outh + DIM;
    #pragma unroll
    for (int r = 0; r < 64; ++r) {
        const float x = v[r];
        const unsigned short hb = f32_to_bf16(x);
        outh[r*64 + lane] = hb;
        outl[r*64 + lane] = f32_to_bf16(x - bf16_to_f32(hb));
    }
}

// ---------------------------------------------------------------------------
// Kernel 2 (exact R6 structure — known-good, no spill): bf16 Gram over
// K_EXT=8192 + fused reduction, triangular grid.  64x64 tile/block, 4 waves
// K-split within each BK=64 stage (mfma_f32_32x32x16, named acc vars),
// 2-stage NAMED-register prefetch (no indexed register arrays — the R7/R8
// array variants spilled ~1 GB to scratch).
// ---------------------------------------------------------------------------
__global__ __launch_bounds__(256) void gram_kernel(const unsigned short* __restrict__ pe,
                                                   const int* __restrict__ labels,
                                                   double* __restrict__ part1,
                                                   double* __restrict__ part2)
{
    __shared__ __align__(16) unsigned short stage[2*64*LDK];   // A | B, 18 KiB
    __shared__ float la[64], lb[64];

    unsigned short* A = stage;
    unsigned short* B = stage + 64*LDK;
    float*  Gt  = (float*)stage;       // alias: live after main loop (64 x 66)
    double* red = (double*)stage;      // alias: live after Gt reads complete

    const int tid = threadIdx.x;
    const int bid = blockIdx.x;

    // triangular index -> (bi,bj), bj >= bi
    int bi = (int)((65.0 - sqrt(65.0*65.0 - 8.0*(double)bid)) * 0.5);
    int start = bi*(65-bi)/2;
    while (bid < start)              { --bi; start = bi*(65-bi)/2; }
    while (bid >= start + (NT - bi)) { start += NT - bi; ++bi; }
    const int bj = bi + (bid - start);

    if (tid < 64)       la[tid]      = 2.0f*(float)labels[bi*64 + tid]      - 1.0f;
    else if (tid < 128) lb[tid - 64] = 2.0f*(float)labels[bj*64 + tid - 64] - 1.0f;

    const int wave = tid >> 6, lane = tid & 63;
    const int mrow = lane & 31;
    const int kgrp = (lane >> 5) * 8;   // A/B layout: lane holds M[lane&31][(lane>>5)*8+j]
    const int ro   = wave*16 + kgrp;    // this wave's k-offset within the stage

    floatx16 acc00, acc01, acc10, acc11;
    #pragma unroll
    for (int i = 0; i < 16; ++i) { acc00[i]=0.f; acc01[i]=0.f; acc10[i]=0.f; acc11[i]=0.f; }

    // staging map: thread -> row sr (0..63), 16B chunks at c0 and c0+32 (ushort)
    const int sr = tid >> 2;
    const int c0 = (tid & 3) * 8;
    const unsigned short* gA = pe + ((size_t)bi*64 + sr) * K_EXT + c0;
    const unsigned short* gB = pe + ((size_t)bj*64 + sr) * K_EXT + c0;
    unsigned short* sA = &A[sr*LDK + c0];
    unsigned short* sB = &B[sr*LDK + c0];

    // prologue: stage 0 -> r*, stage 1 -> s*
    uint4 ra0 = *(const uint4*)(gA +  0), ra1 = *(const uint4*)(gA + 32);
    uint4 rb0 = *(const uint4*)(gB +  0), rb1 = *(const uint4*)(gB + 32);
    uint4 sa0 = *(const uint4*)(gA + 64), sa1 = *(const uint4*)(gA + 96);
    uint4 sb0 = *(const uint4*)(gB + 64), sb1 = *(const uint4*)(gB + 96);

    for (int kk = 0; kk < K_EXT; kk += 2*BK) {
        // ---- phase A: stage kk ----
        __syncthreads();                       // prev readers done
        *(uint4*)(sA +  0) = ra0; *(uint4*)(sA + 32) = ra1;
        *(uint4*)(sB +  0) = rb0; *(uint4*)(sB + 32) = rb1;
        __syncthreads();
        if (kk + 128 < K_EXT) {                // prefetch stage kk+128
            ra0 = *(const uint4*)(gA + kk + 128); ra1 = *(const uint4*)(gA + kk + 160);
            rb0 = *(const uint4*)(gB + kk + 128); rb1 = *(const uint4*)(gB + kk + 160);
        }
        {
            const bf16x8 av0 = *(const bf16x8*)&A[(mrow     )*LDK + ro];
            const bf16x8 av1 = *(const bf16x8*)&A[(mrow + 32)*LDK + ro];
            const bf16x8 bv0 = *(const bf16x8*)&B[(mrow     )*LDK + ro];
            const bf16x8 bv1 = *(const bf16x8*)&B[(mrow + 32)*LDK + ro];
            acc00 = __builtin_amdgcn_mfma_f32_32x32x16_bf16(av0, bv0, acc00, 0, 0, 0);
            acc01 = __builtin_amdgcn_mfma_f32_32x32x16_bf16(av0, bv1, acc01, 0, 0, 0);
            acc10 = __builtin_amdgcn_mfma_f32_32x32x16_bf16(av1, bv0, acc10, 0, 0, 0);
            acc11 = __builtin_amdgcn_mfma_f32_32x32x16_bf16(av1, bv1, acc11, 0, 0, 0);
        }
        // ---- phase B: stage kk+64 ----
        __syncthreads();
        *(uint4*)(sA +  0) = sa0; *(uint4*)(sA + 32) = sa1;
        *(uint4*)(sB +  0) = sb0; *(uint4*)(sB + 32) = sb1;
        __syncthreads();
        if (kk + 192 < K_EXT) {                // prefetch stage kk+192
            sa0 = *(const uint4*)(gA + kk + 192); sa1 = *(const uint4*)(gA + kk + 224);
            sb0 = *(const uint4*)(gB + kk + 192); sb1 = *(const uint4*)(gB + kk + 224);
        }
        {
            const bf16x8 av0 = *(const bf16x8*)&A[(mrow     )*LDK + ro];
            const bf16x8 av1 = *(const bf16x8*)&A[(mrow + 32)*LDK + ro];
            const bf16x8 bv0 = *(const bf16x8*)&B[(mrow     )*LDK + ro];
            const bf16x8 bv1 = *(const bf16x8*)&B[(mrow + 32)*LDK + ro];
            acc00 = __builtin_amdgcn_mfma_f32_32x32x16_bf16(av0, bv0, acc00, 0, 0, 0);
            acc01 = __builtin_amdgcn_mfma_f32_32x32x16_bf16(av0, bv1, acc01, 0, 0, 0);
            acc10 = __builtin_amdgcn_mfma_f32_32x32x16_bf16(av1, bv0, acc10, 0, 0, 0);
            acc11 = __builtin_amdgcn_mfma_f32_32x32x16_bf16(av1, bv1, acc11, 0, 0, 0);
        }
    }

    __syncthreads();   // all staging reads done; stage memory reusable as Gt

    // Sum the 4 wave K-partials into Gt.  C/D layout (m74/m101):
    // row_local = (reg&3) + 8*(reg>>2) + 4*(lane>>5), col_local = lane&31.
    const int crow = (lane >> 5) * 4;
    const int ccol = lane & 31;
    for (int w = 0; w < 4; ++w) {
        if (wave == w) {
            #pragma unroll
            for (int r = 0; r < 16; ++r) {
                const int rl = (r & 3) + 8*(r >> 2) + crow;
                if (w == 0) {
                    Gt[(rl     )*66 + ccol     ] = acc00[r];
                    Gt[(rl     )*66 + ccol + 32] = acc01[r];
                    Gt[(rl + 32)*66 + ccol     ] = acc10[r];
                    Gt[(rl + 32)*66 + ccol + 32] = acc11[r];
                } else {
                    Gt[(rl     )*66 + ccol     ] += acc00[r];
                    Gt[(rl     )*66 + ccol + 32] += acc01[r];
                    Gt[(rl + 32)*66 + ccol     ] += acc10[r];
                    Gt[(rl + 32)*66 + ccol + 32] += acc11[r];
                }
            }
        }
        __syncthreads();
    }

    // Reduce: s1 += w*l_i*l_j*G^2, s2 += w*G^4 (w = 2 above diag, 1 on, 0 below)
    double s1 = 0.0, s2 = 0.0;
    #pragma unroll
    for (int u = 0; u < 16; ++u) {
        const int e   = u*256 + tid;
        const int row = e >> 6, col = e & 63;
        const float g = Gt[row*66 + col];
        const float w = (bi < bj) ? 2.0f : ((row < col) ? 2.0f : ((row == col) ? 1.0f : 0.0f));
        const float g2 = g * g;
        s1 += (double)(w * la[row] * lb[col] * g2);
        const double d = (double)g2;
        s2 += (double)w * d * d;
    }
    __syncthreads();   // Gt reads done before red alias is written

    red[tid] = s1; __syncthreads();
    for (int off = 128; off; off >>= 1) { if (tid < off) red[tid] += red[tid+off]; __syncthreads(); }
    if (tid == 0) part1[bid] = red[0];
    __syncthreads();
    red[tid] = s2; __syncthreads();
    for (int off = 128; off; off >>= 1) { if (tid < off) red[tid] += red[tid+off]; __syncthreads(); }
    if (tid == 0) part2[bid] = red[0];
}

// ---------------------------------------------------------------------------
// Kernel 3: reduce 528 partial slots -> scalar f32.
// square_sum_l = N^2 exactly, so out = s1 / (N * sqrt(s2)).
// ---------------------------------------------------------------------------
__global__ __launch_bounds__(256) void finalize_kernel(const double* __restrict__ part1,
                                                       const double* __restrict__ part2,
                                                       float* __restrict__ out)
{
    __shared__ double r1[256], r2[256];
    const int tid = threadIdx.x;
    double a = 0.0, b = 0.0;
    #pragma unroll
    for (int u = 0; u < 3; ++u) {
        const int s = tid + u*256;
        if (s < NTRI) { a += part1[s]; b += part2[s]; }
    }
    r1[tid] = a; r2[tid] = b; __syncthreads();
    for (int off = 128; off; off >>= 1) {
        if (tid < off) { r1[tid] += r1[tid+off]; r2[tid] += r2[tid+off]; }
        __syncthreads();
    }
    if (tid == 0) out[0] = (float)(r1[0] / (sqrt(r2[0]) * (double)NSAMP));
}

// ---------------------------------------------------------------------------
extern "C" void kernel_launch(void* const* d_in, const int* in_sizes, int n_in,
                              void* d_out, int out_size, void* d_ws, size_t ws_size,
                              hipStream_t stream)
{
    const float* data   = (const float*)d_in[0]; // (2048,12) f32
    const int*   labels = (const int*)d_in[1];   // (2048,)   i32
    const float* params = (const float*)d_in[2]; // (3,12)    f32

    double* part1 = (double*)d_ws;                                    // 528 doubles
    double* part2 = part1 + NTRI;                                     // 528 doubles
    unsigned short* psi_ext = (unsigned short*)((char*)d_ws + 16384); // 2048x8192 bf16 = 32 MiB

    sim_kernel<<<NSAMP/4, 256, 0, stream>>>(data, params, psi_ext);
    gram_kernel<<<NTRI, 256, 0, stream>>>(psi_ext, labels, part1, part2);
    finalize_kernel<<<1, 256, 0, stream>>>(part1, part2, (float*)d_out);
}